// Round 12
// baseline (351.244 us; speedup 1.0000x reference)
//
#include <hip/hip_runtime.h>

#define IN_F 128
#define OUT_F 128
#define MSG_GRID 2048

typedef unsigned int uint;
typedef unsigned short ushort;
typedef __attribute__((ext_vector_type(8))) short bf16x8;
typedef __attribute__((ext_vector_type(4))) float f32x4;
typedef __attribute__((ext_vector_type(4))) float f32x4e;
typedef __attribute__((ext_vector_type(2))) float f32x2e;
typedef __attribute__((ext_vector_type(4))) int i32x4;
typedef __attribute__((ext_vector_type(2))) uint u32x2e;

typedef __attribute__((address_space(1))) void gvoid;
typedef __attribute__((address_space(3))) void svoid;

__device__ __forceinline__ void gl_lds16(const void* g, void* l) {
  __builtin_amdgcn_global_load_lds((const gvoid*)g, (svoid*)l, 16, 0, 0);
}

__device__ inline ushort f2bf(float f) {
  uint u = __float_as_uint(f);
  uint r = (u + 0x7FFFu + ((u >> 16) & 1u)) >> 16;
  return (ushort)r;
}

// ---- Kernel 1: fused {basis-combine+transpose+bf16 weights | x->bf16 | hist/deg}
// hist role now keys on (relation, src>>8) -> binhist for src-locality sort.
__global__ __launch_bounds__(256) void k_prep(
    const float* __restrict__ w, const float* __restrict__ coef,
    const float* __restrict__ selfw, ushort* __restrict__ rwT,
    const float* __restrict__ x, ushort* __restrict__ xbf, int n4,
    const int* __restrict__ etype, const int* __restrict__ src,
    const int* __restrict__ tgt, int E, int R, int B,
    int* __restrict__ binhist, int* __restrict__ ideg, int wblocks, int xblocks) {
  __shared__ float t[64][65];
  int tid = threadIdx.x;
  int bid = blockIdx.x;

  if (bid < wblocks) {                       // weight-prep role
    int r = bid >> 2;
    int i0 = (bid & 1) * 64;
    int o0 = ((bid >> 1) & 1) * 64;
    float4 a4[4];
    if (r < R) {
      #pragma unroll
      for (int it = 0; it < 4; ++it) a4[it] = make_float4(0.f, 0.f, 0.f, 0.f);
      for (int b = 0; b < B; ++b) {
        float cb = coef[r * B + b];
        const float4* w4 = (const float4*)w + (size_t)b * 4096;
        #pragma unroll
        for (int it = 0; it < 4; ++it) {
          int idx = it * 256 + tid;
          int i = idx >> 4, c4 = idx & 15;
          float4 v = w4[(i0 + i) * 32 + (o0 >> 2) + c4];
          a4[it].x = fmaf(cb, v.x, a4[it].x);
          a4[it].y = fmaf(cb, v.y, a4[it].y);
          a4[it].z = fmaf(cb, v.z, a4[it].z);
          a4[it].w = fmaf(cb, v.w, a4[it].w);
        }
      }
    } else {
      const float4* w4 = (const float4*)selfw;
      #pragma unroll
      for (int it = 0; it < 4; ++it) {
        int idx = it * 256 + tid;
        int i = idx >> 4, c4 = idx & 15;
        a4[it] = w4[(i0 + i) * 32 + (o0 >> 2) + c4];
      }
    }
    #pragma unroll
    for (int it = 0; it < 4; ++it) {
      int idx = it * 256 + tid;
      int i = idx >> 4, c4 = idx & 15;
      t[i][c4 * 4 + 0] = a4[it].x; t[i][c4 * 4 + 1] = a4[it].y;
      t[i][c4 * 4 + 2] = a4[it].z; t[i][c4 * 4 + 3] = a4[it].w;
    }
    __syncthreads();
    ushort* dst = rwT + (size_t)r * IN_F * OUT_F;
    #pragma unroll
    for (int it = 0; it < 4; ++it) {
      int idx = it * 256 + tid;
      int o = idx >> 4, cc = idx & 15;
      uint2 pk;
      pk.x = (uint)f2bf(t[cc * 4 + 0][o]) | ((uint)f2bf(t[cc * 4 + 1][o]) << 16);
      pk.y = (uint)f2bf(t[cc * 4 + 2][o]) | ((uint)f2bf(t[cc * 4 + 3][o]) << 16);
      *(uint2*)(dst + (o0 + o) * IN_F + i0 + cc * 4) = pk;
    }
    return;
  }
  bid -= wblocks;
  if (bid < xblocks) {                        // x conversion role
    int i = bid * 256 + tid;
    if (i < n4) {
      f32x4e v = __builtin_nontemporal_load((const f32x4e*)x + i);
      uint2 pk;
      pk.x = (uint)f2bf(v.x) | ((uint)f2bf(v.y) << 16);
      pk.y = (uint)f2bf(v.z) | ((uint)f2bf(v.w) << 16);
      ((uint2*)xbf)[i] = pk;
    }
    return;
  }
  bid -= xblocks;                             // bin-histogram + degree role
  int e = bid * 256 + tid;
  if (e < E) {
    int bin = etype[e] * 256 + (src[e] >> 8);   // ~78 edges/bin: low contention
    atomicAdd(&binhist[bin], 1);
    atomicAdd(&ideg[tgt[e]], 1);
  }
}

// ---- Kernel 2: bin scan (NB=R*256) + offs/toffs + node-degree scan -----------
__global__ __launch_bounds__(1024) void k_scans(
    const int* __restrict__ binhist, int* __restrict__ binoff,
    int* __restrict__ offs, int* __restrict__ toffs, int R, int NB,
    const int* __restrict__ ideg, int* __restrict__ row_off, int N) {
  __shared__ int part[1024];
  int tid = threadIdx.x;

  // phase 1: exclusive scan of binhist[NB] -> binoff
  int bchunk = (NB + 1023) >> 10;
  int blo = min(tid * bchunk, NB), bhi = min(blo + bchunk, NB);
  int s = 0;
  for (int i = blo; i < bhi; ++i) s += binhist[i];
  part[tid] = s;
  __syncthreads();
  for (int d = 1; d < 1024; d <<= 1) {
    int v = (tid >= d) ? part[tid - d] : 0;
    __syncthreads();
    part[tid] += v;
    __syncthreads();
  }
  int pre = (tid > 0) ? part[tid - 1] : 0;
  for (int i = blo; i < bhi; ++i) { binoff[i] = pre; pre += binhist[i]; }
  if (tid == 1023) binoff[NB] = part[1023];
  __syncthreads();
  if (tid == 0) {
    for (int r = 0; r < R; ++r) offs[r] = binoff[r * 256];
    offs[R] = binoff[NB];
    int tt = 0;
    for (int r = 0; r < R; ++r) {
      toffs[r] = tt;
      tt += (offs[r + 1] - offs[r] + 63) >> 6;
    }
    toffs[R] = tt;
  }

  // phase 2: node-degree exclusive scan
  int chunk = (((N + 1023) >> 10) + 3) & ~3;
  int lo = min(tid * chunk, N), hi = min(lo + chunk, N);
  int s2 = 0;
  int i = lo;
  for (; i + 4 <= hi; i += 4) {
    i32x4 v = *(const i32x4*)(ideg + i);
    s2 += v.x + v.y + v.z + v.w;
  }
  for (; i < hi; ++i) s2 += ideg[i];
  __syncthreads();
  part[tid] = s2;
  __syncthreads();
  for (int d = 1; d < 1024; d <<= 1) {
    int v = (tid >= d) ? part[tid - d] : 0;
    __syncthreads();
    part[tid] += v;
    __syncthreads();
  }
  pre = (tid > 0) ? part[tid - 1] : 0;
  i = lo;
  for (; i + 4 <= hi; i += 4) {
    i32x4 v = *(const i32x4*)(ideg + i);
    i32x4 o;
    o.x = pre; o.y = pre + v.x; o.z = o.y + v.y; o.w = o.z + v.z;
    pre = o.w + v.w;
    *(i32x4*)(row_off + i) = o;
  }
  for (; i < hi; ++i) { row_off[i] = pre; pre += ideg[i]; }
  if (tid == 1023) row_off[N] = part[1023];
}

// ---- Kernel 3: (rel, src-bucket) counting-sort scatter -----------------------
// perm within each relation is now src-ascending (by bucket) -> k_msg's tile
// gathers hit a ~50KB xbf window -> L2/L3-local.
__global__ void k_scatter2(const int* __restrict__ etype, const int* __restrict__ src,
                           const int* __restrict__ tgt, int E,
                           const int* __restrict__ binoff, const int* __restrict__ row_off,
                           int* __restrict__ bincur, int* __restrict__ cur_t,
                           int* __restrict__ perm, int* __restrict__ wpos) {
  int e = blockIdx.x * blockDim.x + threadIdx.x;
  if (e >= E) return;
  int s = src[e];
  int bin = etype[e] * 256 + (s >> 8);
  int pos = binoff[bin] + atomicAdd(&bincur[bin], 1);
  perm[pos] = s;
  int tg = tgt[e];
  wpos[pos] = row_off[tg] + atomicAdd(&cur_t[tg], 1);
}

// ---- Kernel 4: persistent reg-staged double-buffered MFMA msg GEMM -----------
// (round-8 proven version, unchanged) Sync: ONE {lgkmcnt(0); s_barrier;
// sched_barrier(0)} per tile. All global traffic is private VGPR loads/stores.
__global__ __launch_bounds__(256) void k_msg(
    const ushort* __restrict__ xbf, const int* __restrict__ perm,
    const int* __restrict__ wpos, const int* __restrict__ offs,
    const int* __restrict__ toffs, const ushort* __restrict__ rwT,
    ushort* __restrict__ msg, int R) {
  __shared__ ushort xs[2][64 * IN_F];   // 32 KB double buffer (XOR-swizzled)
  __shared__ int soff[48], stoff[48];
  int tid = threadIdx.x, wv = tid >> 6, l = tid & 63, g = l >> 4, ln = l & 15;
  int wc = wv * 32;
  int trow = tid >> 4, ts4 = tid & 15;

  if (tid <= R) { soff[tid] = offs[tid]; stoff[tid] = toffs[tid]; }
  __syncthreads();
  int ntiles = stoff[R];
  int chunkT = (ntiles + MSG_GRID - 1) / MSG_GRID;
  int t0 = blockIdx.x * chunkT;
  int tend = min(t0 + chunkT, ntiles);
  if (t0 >= tend) return;

  bf16x8 bfr[2][4];
#define LOADW(rr)                                                             \
  {                                                                           \
    const ushort* _wp = rwT + (size_t)(rr) * IN_F * OUT_F;                    \
    _Pragma("unroll")                                                         \
    for (int _n = 0; _n < 2; ++_n)                                            \
      _Pragma("unroll")                                                       \
      for (int _kk = 0; _kk < 4; ++_kk)                                       \
        bfr[_n][_kk] = *(const bf16x8*)(_wp + (wc + _n * 16 + ln) * IN_F +    \
                                        _kk * 32 + g * 8);                    \
  }

  // ---- prologue: fill pipeline (depth 3: perm -> x regs -> ds_write) ----
  int r0 = 0;
  while (t0 >= stoff[r0 + 1]) ++r0;

  bf16x8 xreg[4];
  int srcrow[4], wq[4];

  {
    int eb = soff[r0] + (t0 - stoff[r0]) * 64;
    int cnt = min(64, soff[r0 + 1] - eb);
    #pragma unroll
    for (int i = 0; i < 4; ++i) {
      int row = trow + 16 * i;
      int sr = perm[eb + min(row, cnt - 1)];
      xreg[i] = *(const bf16x8*)(xbf + (size_t)sr * IN_F + ts4 * 8);
    }
    #pragma unroll
    for (int i = 0; i < 4; ++i) {
      int row = trow + 16 * i;
      *(bf16x8*)((char*)xs[0] + row * 256 + ((ts4 * 16) ^ ((row & 7) << 4))) = xreg[i];
    }
    #pragma unroll
    for (int q = 0; q < 4; ++q) wq[q] = wpos[eb + min(q * 16 + ln, cnt - 1)];
  }
  if (t0 + 1 < tend) {
    int r1 = r0; while (t0 + 1 >= stoff[r1 + 1]) ++r1;
    int eb = soff[r1] + (t0 + 1 - stoff[r1]) * 64;
    int cnt = min(64, soff[r1 + 1] - eb);
    #pragma unroll
    for (int i = 0; i < 4; ++i) {
      int row = trow + 16 * i;
      int sr = perm[eb + min(row, cnt - 1)];
      xreg[i] = *(const bf16x8*)(xbf + (size_t)sr * IN_F + ts4 * 8);
    }
  }
  if (t0 + 2 < tend) {
    int r2 = r0; while (t0 + 2 >= stoff[r2 + 1]) ++r2;
    int eb = soff[r2] + (t0 + 2 - stoff[r2]) * 64;
    int cnt = min(64, soff[r2 + 1] - eb);
    #pragma unroll
    for (int i = 0; i < 4; ++i)
      srcrow[i] = perm[eb + min(trow + 16 * i, cnt - 1)];
  }
  LOADW(r0)
  int r_loaded = r0;
  int rcw = r0, rw1 = r0, rw3 = r0;   // walkers for t, t+1, t+3 (monotone)
  int cur = 0;

  for (int t = t0; t < tend; ++t) {
    // C: the one barrier per tile — drains LDS writes AND reads (RAW + WAR)
    asm volatile("s_waitcnt lgkmcnt(0)" ::: "memory");
    __builtin_amdgcn_s_barrier();
    __builtin_amdgcn_sched_barrier(0);

    // D: tile meta + W fragments (rare relation change), then MFMA
    while (t >= stoff[rcw + 1]) ++rcw;
    int eb_t = soff[rcw] + (t - stoff[rcw]) * 64;
    int cnt_t = min(64, soff[rcw + 1] - eb_t);
    if (rcw != r_loaded) { LOADW(rcw) r_loaded = rcw; }

    const char* xb = (const char*)xs[cur];
    f32x4 acc[2][4] = {};   // D: col=edge (lane&15), row=out-channel (g*4+j)
    #pragma unroll
    for (int kk = 0; kk < 4; ++kk) {
      bf16x8 a[4];
      #pragma unroll
      for (int q = 0; q < 4; ++q) {
        int row = q * 16 + ln;
        int kb = kk * 64 + g * 16;
        a[q] = *(const bf16x8*)(xb + row * 256 + (kb ^ ((row & 7) << 4)));
      }
      #pragma unroll
      for (int n = 0; n < 2; ++n)
        #pragma unroll
        for (int q = 0; q < 4; ++q)
          acc[n][q] = __builtin_amdgcn_mfma_f32_16x16x32_bf16(bfr[n][kk], a[q],
                                                              acc[n][q], 0, 0, 0);
    }

    // E: wide cached stores (8B x2 per edge-quarter per lane)
    #pragma unroll
    for (int q = 0; q < 4; ++q) {
      int rr = q * 16 + ln;
      if (rr < cnt_t) {
        ushort* mp = msg + (size_t)wq[q] * OUT_F + wc + g * 4;
        uint2 p0, p1;
        p0.x = (uint)f2bf(acc[0][q][0]) | ((uint)f2bf(acc[0][q][1]) << 16);
        p0.y = (uint)f2bf(acc[0][q][2]) | ((uint)f2bf(acc[0][q][3]) << 16);
        p1.x = (uint)f2bf(acc[1][q][0]) | ((uint)f2bf(acc[1][q][1]) << 16);
        p1.y = (uint)f2bf(acc[1][q][2]) | ((uint)f2bf(acc[1][q][3]) << 16);
        *(uint2*)mp = p0;          // cols wc+g*4 .. +3
        *(uint2*)(mp + 16) = p1;   // cols wc+16+g*4 .. +3
      }
    }

    // A: ds_write x(t+1) regs -> other buffer (visible after next C)
    if (t + 1 < tend) {
      char* xw = (char*)xs[cur ^ 1];
      #pragma unroll
      for (int i = 0; i < 4; ++i) {
        int row = trow + 16 * i;
        *(bf16x8*)(xw + row * 256 + ((ts4 * 16) ^ ((row & 7) << 4))) = xreg[i];
      }
    }

    // B: issue next loads (latency hidden across the next barrier+MFMA)
    if (t + 2 < tend) {
      #pragma unroll
      for (int i = 0; i < 4; ++i)
        xreg[i] = *(const bf16x8*)(xbf + (size_t)srcrow[i] * IN_F + ts4 * 8);
    }
    if (t + 3 < tend) {
      while (t + 3 >= stoff[rw3 + 1]) ++rw3;
      int eb = soff[rw3] + (t + 3 - stoff[rw3]) * 64;
      int cnt = min(64, soff[rw3 + 1] - eb);
      #pragma unroll
      for (int i = 0; i < 4; ++i)
        srcrow[i] = perm[eb + min(trow + 16 * i, cnt - 1)];
    }
    if (t + 1 < tend) {
      while (t + 1 >= stoff[rw1 + 1]) ++rw1;
      int eb = soff[rw1] + (t + 1 - stoff[rw1]) * 64;
      int cnt = min(64, soff[rw1 + 1] - eb);
      #pragma unroll
      for (int q = 0; q < 4; ++q) wq[q] = wpos[eb + min(q * 16 + ln, cnt - 1)];
    }
    cur ^= 1;
  }
#undef LOADW
}

// ---- Kernel 5: fused self MFMA + per-node aggregation + bias + out -----------
__global__ __launch_bounds__(256) void k_out(
    const ushort* __restrict__ xbf, const ushort* __restrict__ swT,
    const float* __restrict__ bias, const ushort* __restrict__ msg,
    const int* __restrict__ row_off, float* __restrict__ out, int N) {
  __shared__ float smem[64 * 128];   // 32 KB; first 16 KB doubles as bf16 x-tile
  __shared__ int rof[65];            // block's row_off slice (kills serial loads)
  int tid = threadIdx.x;
  int base = blockIdx.x * 64;
  int wv = tid >> 6, l = tid & 63;
  char* xb = (char*)smem;

  #pragma unroll
  for (int i = 0; i < 4; ++i) {
    int idx = i * 256 + tid;
    int row = idx >> 4, s4 = idx & 15;
    int c = s4 ^ (row & 7);
    int n = base + row;
    char* lb = xb + i * 4096 + wv * 1024;
    if (n < N)
      gl_lds16(xbf + (size_t)n * IN_F + c * 8, lb);
  }
  if (tid < 65) rof[tid] = row_off[min(base + tid, N)];

  int g = l >> 4, ln = l & 15, wc = wv * 32;
  bf16x8 bfr[2][4];
  #pragma unroll
  for (int n = 0; n < 2; ++n)
    #pragma unroll
    for (int kk = 0; kk < 4; ++kk)
      bfr[n][kk] = *(const bf16x8*)(swT + (wc + n * 16 + ln) * IN_F + kk * 32 + g * 8);

  __syncthreads();

  f32x4 acc[4][2] = {};
  #pragma unroll
  for (int kk = 0; kk < 4; ++kk) {
    bf16x8 a[4];
    #pragma unroll
    for (int m = 0; m < 4; ++m) {
      int row = m * 16 + ln;
      int kb = kk * 64 + g * 16;
      a[m] = *(const bf16x8*)(xb + row * 256 + (kb ^ ((row & 7) << 4)));
    }
    #pragma unroll
    for (int m = 0; m < 4; ++m)
      #pragma unroll
      for (int n = 0; n < 2; ++n)
        acc[m][n] = __builtin_amdgcn_mfma_f32_16x16x32_bf16(a[m], bfr[n][kk],
                                                            acc[m][n], 0, 0, 0);
  }

  __syncthreads();   // all xs reads done; reuse smem as fp32 self-result
  #pragma unroll
  for (int m = 0; m < 4; ++m)
    #pragma unroll
    for (int n = 0; n < 2; ++n)
      #pragma unroll
      for (int j = 0; j < 4; ++j)
        smem[(m * 16 + g * 4 + j) * 128 + wc + n * 16 + ln] = acc[m][n][j];
  __syncthreads();

  // aggregation: lane halves split even/odd rows; 8B/lane; shfl_xor combine
  int half = l >> 5, cl = l & 31;
  f32x4e b4 = ((const f32x4e*)bias)[cl];
  for (int q = 0; q < 16; ++q) {
    int n = base + wv * 16 + q;
    if (n >= N) break;
    int lo = rof[wv * 16 + q], hi = rof[wv * 16 + q + 1];
    int len = hi - lo;
    const ushort* mrow = msg + (size_t)(lo + half) * OUT_F + cl * 4;
    float fa0 = 0.f, fa1 = 0.f, fa2 = 0.f, fa3 = 0.f;
#define ACC8(v)                                                  \
    { fa0 += __uint_as_float((v).x << 16);                       \
      fa1 += __uint_as_float((v).x & 0xFFFF0000u);               \
      fa2 += __uint_as_float((v).y << 16);                       \
      fa3 += __uint_as_float((v).y & 0xFFFF0000u); }
    int p = 0;
    for (; p + 8 <= len; p += 8) {
      u32x2e v0 = *(const u32x2e*)(mrow + (size_t)p * OUT_F);
      u32x2e v1 = *(const u32x2e*)(mrow + (size_t)(p + 2) * OUT_F);
      u32x2e v2 = *(const u32x2e*)(mrow + (size_t)(p + 4) * OUT_F);
      u32x2e v3 = *(const u32x2e*)(mrow + (size_t)(p + 6) * OUT_F);
      ACC8(v0) ACC8(v1) ACC8(v2) ACC8(v3)
    }
    for (; p + 2 <= len; p += 2) {
      u32x2e v = *(const u32x2e*)(mrow + (size_t)p * OUT_F);
      ACC8(v)
    }
    if (p < len && half == 0) {
      u32x2e v = *(const u32x2e*)(mrow + (size_t)p * OUT_F);
      ACC8(v)
    }
#undef ACC8
    fa0 += __shfl_xor(fa0, 32);
    fa1 += __shfl_xor(fa1, 32);
    fa2 += __shfl_xor(fa2, 32);
    fa3 += __shfl_xor(fa3, 32);
    if (half == 0) {
      float inv = 1.f / (float)max(len, 1);
      int rloc = wv * 16 + q;
      f32x4e s4 = *(const f32x4e*)(&smem[rloc * 128 + cl * 4]);
      f32x4e o = {fa0 * inv + s4.x + b4.x, fa1 * inv + s4.y + b4.y,
                  fa2 * inv + s4.z + b4.z, fa3 * inv + s4.w + b4.w};
      __builtin_nontemporal_store(o, (f32x4e*)(out + (size_t)n * OUT_F + cl * 4));
    }
  }
}

// ------------------------------- launch ---------------------------------------
extern "C" void kernel_launch(void* const* d_in, const int* in_sizes, int n_in,
                              void* d_out, int out_size, void* d_ws, size_t ws_size,
                              hipStream_t stream) {
  const float* x      = (const float*)d_in[0];
  const int*   ei     = (const int*)d_in[1];   // [2][E]
  const int*   etype  = (const int*)d_in[2];   // [E]
  const float* weight = (const float*)d_in[4]; // [B][128][128]
  const float* coeff  = (const float*)d_in[5]; // [R][B]
  const float* selfw  = (const float*)d_in[6]; // [128][128]
  const float* bias   = (const float*)d_in[7]; // [128]

  int N = in_sizes[0] / IN_F;
  int E = in_sizes[2];
  int B = in_sizes[4] / (IN_F * OUT_F);
  int R = in_sizes[5] / B;
  const int* src = ei;
  const int* tgt = ei + E;
  int NB = R * 256;          // (relation, src>>8) bins

  char* ws = (char*)d_ws;
  size_t off = 0;
  auto alloc = [&](size_t bytes) {
    char* p = ws + off;
    off += (bytes + 255) & ~(size_t)255;
    return p;
  };
  ushort* rwT     = (ushort*)alloc((size_t)(R + 1) * IN_F * OUT_F * 2);
  ushort* xbf     = (ushort*)alloc((size_t)N * IN_F * 2);
  int*    perm    = (int*)alloc((size_t)E * 4);
  int*    wpos    = (int*)alloc((size_t)E * 4);
  int*    row_off = (int*)alloc((size_t)(N + 1) * 4);
  int*    binoff  = (int*)alloc((size_t)(NB + 1) * 4);
  // zero region: ideg[N] | cur_t[N] | binhist[NB] | bincur[NB]
  int*    ideg    = (int*)alloc((size_t)(2 * N + 2 * NB) * 4);
  int*    cur_t   = ideg + N;
  int*    binhist = cur_t + N;
  int*    bincur  = binhist + NB;
  int*    offs    = (int*)alloc(64 * 4);
  int*    toffs   = (int*)alloc(64 * 4);
  ushort* msg     = (ushort*)alloc((size_t)E * OUT_F * 2);

  (void)hipMemsetAsync(ideg, 0, (size_t)(2 * N + 2 * NB) * 4, stream);

  int n4 = N * IN_F / 4;
  int wblocks = (R + 1) * 4;
  int xblocks = (n4 + 255) / 256;
  int hblocks = (E + 255) / 256;
  k_prep<<<wblocks + xblocks + hblocks, 256, 0, stream>>>(
      weight, coeff, selfw, rwT, x, xbf, n4, etype, src, tgt, E, R, B,
      binhist, ideg, wblocks, xblocks);
  k_scans<<<1, 1024, 0, stream>>>(binhist, binoff, offs, toffs, R, NB,
                                  ideg, row_off, N);
  k_scatter2<<<hblocks, 256, 0, stream>>>(etype, src, tgt, E, binoff, row_off,
                                          bincur, cur_t, perm, wpos);
  k_msg<<<MSG_GRID, 256, 0, stream>>>(xbf, perm, wpos, offs, toffs, rwT, msg, R);
  k_out<<<(N + 63) / 64, 256, 0, stream>>>(xbf, rwT + (size_t)R * IN_F * OUT_F,
                                           bias, msg, row_off, (float*)d_out, N);
}

// Round 13
// 274.948 us; speedup vs baseline: 1.2775x; 1.2775x over previous
//
#include <hip/hip_runtime.h>

#define IN_F 128
#define OUT_F 128
#define MSG_GRID 1024
#define SC_CHUNK 1536

typedef unsigned int uint;
typedef unsigned short ushort;
typedef __attribute__((ext_vector_type(8))) short bf16x8;
typedef __attribute__((ext_vector_type(4))) float f32x4;
typedef __attribute__((ext_vector_type(4))) float f32x4e;
typedef __attribute__((ext_vector_type(2))) float f32x2e;
typedef __attribute__((ext_vector_type(4))) int i32x4;
typedef __attribute__((ext_vector_type(2))) uint u32x2e;

typedef __attribute__((address_space(1))) void gvoid;
typedef __attribute__((address_space(3))) void svoid;

__device__ __forceinline__ void gl_lds16(const void* g, void* l) {
  __builtin_amdgcn_global_load_lds((const gvoid*)g, (svoid*)l, 16, 0, 0);
}

__device__ inline ushort f2bf(float f) {
  uint u = __float_as_uint(f);
  uint r = (u + 0x7FFFu + ((u >> 16) & 1u)) >> 16;
  return (ushort)r;
}

// ---- Kernel 1: fused {basis-combine+transpose+bf16 weights | x->bf16 | hist/deg}
__global__ __launch_bounds__(256) void k_prep(
    const float* __restrict__ w, const float* __restrict__ coef,
    const float* __restrict__ selfw, ushort* __restrict__ rwT,
    const float* __restrict__ x, ushort* __restrict__ xbf, int n4,
    const int* __restrict__ etype, const int* __restrict__ tgt, int E, int R, int B,
    int* __restrict__ hist, int* __restrict__ ideg, int wblocks, int xblocks) {
  __shared__ float t[64][65];
  __shared__ int lh[64];
  int tid = threadIdx.x;
  int bid = blockIdx.x;

  if (bid < wblocks) {                       // weight-prep role
    int r = bid >> 2;
    int i0 = (bid & 1) * 64;
    int o0 = ((bid >> 1) & 1) * 64;
    float4 a4[4];
    if (r < R) {
      #pragma unroll
      for (int it = 0; it < 4; ++it) a4[it] = make_float4(0.f, 0.f, 0.f, 0.f);
      for (int b = 0; b < B; ++b) {
        float cb = coef[r * B + b];
        const float4* w4 = (const float4*)w + (size_t)b * 4096;
        #pragma unroll
        for (int it = 0; it < 4; ++it) {
          int idx = it * 256 + tid;
          int i = idx >> 4, c4 = idx & 15;
          float4 v = w4[(i0 + i) * 32 + (o0 >> 2) + c4];
          a4[it].x = fmaf(cb, v.x, a4[it].x);
          a4[it].y = fmaf(cb, v.y, a4[it].y);
          a4[it].z = fmaf(cb, v.z, a4[it].z);
          a4[it].w = fmaf(cb, v.w, a4[it].w);
        }
      }
    } else {
      const float4* w4 = (const float4*)selfw;
      #pragma unroll
      for (int it = 0; it < 4; ++it) {
        int idx = it * 256 + tid;
        int i = idx >> 4, c4 = idx & 15;
        a4[it] = w4[(i0 + i) * 32 + (o0 >> 2) + c4];
      }
    }
    #pragma unroll
    for (int it = 0; it < 4; ++it) {
      int idx = it * 256 + tid;
      int i = idx >> 4, c4 = idx & 15;
      t[i][c4 * 4 + 0] = a4[it].x; t[i][c4 * 4 + 1] = a4[it].y;
      t[i][c4 * 4 + 2] = a4[it].z; t[i][c4 * 4 + 3] = a4[it].w;
    }
    __syncthreads();
    ushort* dst = rwT + (size_t)r * IN_F * OUT_F;
    #pragma unroll
    for (int it = 0; it < 4; ++it) {
      int idx = it * 256 + tid;
      int o = idx >> 4, cc = idx & 15;
      uint2 pk;
      pk.x = (uint)f2bf(t[cc * 4 + 0][o]) | ((uint)f2bf(t[cc * 4 + 1][o]) << 16);
      pk.y = (uint)f2bf(t[cc * 4 + 2][o]) | ((uint)f2bf(t[cc * 4 + 3][o]) << 16);
      *(uint2*)(dst + (o0 + o) * IN_F + i0 + cc * 4) = pk;
    }
    return;
  }
  bid -= wblocks;
  if (bid < xblocks) {                        // x conversion role
    int i = bid * 256 + tid;
    if (i < n4) {
      f32x4e v = __builtin_nontemporal_load((const f32x4e*)x + i);
      uint2 pk;
      pk.x = (uint)f2bf(v.x) | ((uint)f2bf(v.y) << 16);
      pk.y = (uint)f2bf(v.z) | ((uint)f2bf(v.w) << 16);
      ((uint2*)xbf)[i] = pk;
    }
    return;
  }
  bid -= xblocks;                             // histogram + degree role
  if (tid < R) lh[tid] = 0;
  __syncthreads();
  int e = bid * 256 + tid;
  if (e < E) {
    atomicAdd(&lh[etype[e]], 1);
    atomicAdd(&ideg[tgt[e]], 1);
  }
  __syncthreads();
  if (tid < R && lh[tid]) atomicAdd(&hist[tid], lh[tid]);
}

// ---- Kernel 2: R-bin scan + node-degree exclusive scan -----------------------
__global__ __launch_bounds__(1024) void k_scans(
    const int* __restrict__ hist, int* __restrict__ offs, int* __restrict__ toffs,
    int R, const int* __restrict__ ideg, int* __restrict__ row_off, int N) {
  __shared__ int part[1024];
  int tid = threadIdx.x;
  if (tid == 0) {
    int s = 0, tt = 0;
    for (int r = 0; r < R; ++r) {
      offs[r] = s; toffs[r] = tt;
      s += hist[r];
      tt += (hist[r] + 63) >> 6;
    }
    offs[R] = s; toffs[R] = tt;
  }
  int chunk = (((N + 1023) >> 10) + 3) & ~3;
  int lo = min(tid * chunk, N), hi = min(lo + chunk, N);
  int s = 0;
  int i = lo;
  for (; i + 4 <= hi; i += 4) {
    i32x4 v = *(const i32x4*)(ideg + i);
    s += v.x + v.y + v.z + v.w;
  }
  for (; i < hi; ++i) s += ideg[i];
  part[tid] = s;
  __syncthreads();
  for (int d = 1; d < 1024; d <<= 1) {
    int v = (tid >= d) ? part[tid - d] : 0;
    __syncthreads();
    part[tid] += v;
    __syncthreads();
  }
  int pre = (tid > 0) ? part[tid - 1] : 0;
  i = lo;
  for (; i + 4 <= hi; i += 4) {
    i32x4 v = *(const i32x4*)(ideg + i);
    i32x4 o;
    o.x = pre; o.y = pre + v.x; o.z = o.y + v.y; o.w = o.z + v.z;
    pre = o.w + v.w;
    *(i32x4*)(row_off + i) = o;
  }
  for (; i < hi; ++i) { row_off[i] = pre; pre += ideg[i]; }
  if (tid == 1023) row_off[N] = part[1023];
}

// ---- Kernel 3: counting-sort scatter, chunked (low cur_r contention) ---------
__global__ __launch_bounds__(256) void k_scatter2(
    const int* __restrict__ etype, const int* __restrict__ src,
    const int* __restrict__ tgt, int E, int R,
    const int* __restrict__ offs, const int* __restrict__ row_off,
    int* __restrict__ cur_r, int* __restrict__ cur_t,
    int* __restrict__ perm, int* __restrict__ wpos) {
  __shared__ int lh[64], lbase[64], lcur[64];
  __shared__ unsigned char ety[SC_CHUNK];
  int tid = threadIdx.x;
  int e0 = blockIdx.x * SC_CHUNK;
  int e1 = min(e0 + SC_CHUNK, E);
  if (e0 >= E) return;
  if (tid < R) { lh[tid] = 0; lcur[tid] = 0; }
  __syncthreads();
  for (int e = e0 + tid; e < e1; e += 256) {
    int t = etype[e];
    ety[e - e0] = (unsigned char)t;
    atomicAdd(&lh[t], 1);
  }
  __syncthreads();
  if (tid < R && lh[tid]) lbase[tid] = atomicAdd(&cur_r[tid], lh[tid]);
  __syncthreads();
  for (int e = e0 + tid; e < e1; e += 256) {
    int t = ety[e - e0];
    int loc = atomicAdd(&lcur[t], 1);
    int slot = offs[t] + lbase[t] + loc;
    perm[slot] = src[e];
    int tg = tgt[e];
    wpos[slot] = row_off[tg] + atomicAdd(&cur_t[tg], 1);
  }
}

// ---- Kernel 4: persistent reg-staged double-buffered MFMA msg GEMM -----------
// (round-8 proven version) Sync: ONE {lgkmcnt(0); s_barrier; sched_barrier(0)}
// per tile. All global traffic is private VGPR loads/stores — compiler-tracked.
__global__ __launch_bounds__(256) void k_msg(
    const ushort* __restrict__ xbf, const int* __restrict__ perm,
    const int* __restrict__ wpos, const int* __restrict__ offs,
    const int* __restrict__ toffs, const ushort* __restrict__ rwT,
    ushort* __restrict__ msg, int R) {
  __shared__ ushort xs[2][64 * IN_F];   // 32 KB double buffer (XOR-swizzled)
  __shared__ int soff[48], stoff[48];
  int tid = threadIdx.x, wv = tid >> 6, l = tid & 63, g = l >> 4, ln = l & 15;
  int wc = wv * 32;
  int trow = tid >> 4, ts4 = tid & 15;

  if (tid <= R) { soff[tid] = offs[tid]; stoff[tid] = toffs[tid]; }
  __syncthreads();
  int ntiles = stoff[R];
  int chunkT = (ntiles + MSG_GRID - 1) / MSG_GRID;
  int t0 = blockIdx.x * chunkT;
  int tend = min(t0 + chunkT, ntiles);
  if (t0 >= tend) return;

  bf16x8 bfr[2][4];
#define LOADW(rr)                                                             \
  {                                                                           \
    const ushort* _wp = rwT + (size_t)(rr) * IN_F * OUT_F;                    \
    _Pragma("unroll")                                                         \
    for (int _n = 0; _n < 2; ++_n)                                            \
      _Pragma("unroll")                                                       \
      for (int _kk = 0; _kk < 4; ++_kk)                                       \
        bfr[_n][_kk] = *(const bf16x8*)(_wp + (wc + _n * 16 + ln) * IN_F +    \
                                        _kk * 32 + g * 8);                    \
  }

  // ---- prologue: fill pipeline (depth 3: perm -> x regs -> ds_write) ----
  int r0 = 0;
  while (t0 >= stoff[r0 + 1]) ++r0;

  bf16x8 xreg[4];
  int srcrow[4], wq[4];

  {
    int eb = soff[r0] + (t0 - stoff[r0]) * 64;
    int cnt = min(64, soff[r0 + 1] - eb);
    #pragma unroll
    for (int i = 0; i < 4; ++i) {
      int row = trow + 16 * i;
      int sr = perm[eb + min(row, cnt - 1)];
      xreg[i] = *(const bf16x8*)(xbf + (size_t)sr * IN_F + ts4 * 8);
    }
    #pragma unroll
    for (int i = 0; i < 4; ++i) {
      int row = trow + 16 * i;
      *(bf16x8*)((char*)xs[0] + row * 256 + ((ts4 * 16) ^ ((row & 7) << 4))) = xreg[i];
    }
    #pragma unroll
    for (int q = 0; q < 4; ++q) wq[q] = wpos[eb + min(q * 16 + ln, cnt - 1)];
  }
  if (t0 + 1 < tend) {
    int r1 = r0; while (t0 + 1 >= stoff[r1 + 1]) ++r1;
    int eb = soff[r1] + (t0 + 1 - stoff[r1]) * 64;
    int cnt = min(64, soff[r1 + 1] - eb);
    #pragma unroll
    for (int i = 0; i < 4; ++i) {
      int row = trow + 16 * i;
      int sr = perm[eb + min(row, cnt - 1)];
      xreg[i] = *(const bf16x8*)(xbf + (size_t)sr * IN_F + ts4 * 8);
    }
  }
  if (t0 + 2 < tend) {
    int r2 = r0; while (t0 + 2 >= stoff[r2 + 1]) ++r2;
    int eb = soff[r2] + (t0 + 2 - stoff[r2]) * 64;
    int cnt = min(64, soff[r2 + 1] - eb);
    #pragma unroll
    for (int i = 0; i < 4; ++i)
      srcrow[i] = perm[eb + min(trow + 16 * i, cnt - 1)];
  }
  LOADW(r0)
  int r_loaded = r0;
  int rcw = r0, rw1 = r0, rw3 = r0;   // walkers for t, t+1, t+3 (monotone)
  int cur = 0;

  for (int t = t0; t < tend; ++t) {
    // C: the one barrier per tile — drains LDS writes AND reads (RAW + WAR)
    asm volatile("s_waitcnt lgkmcnt(0)" ::: "memory");
    __builtin_amdgcn_s_barrier();
    __builtin_amdgcn_sched_barrier(0);

    // D: tile meta + W fragments (rare relation change), then MFMA
    while (t >= stoff[rcw + 1]) ++rcw;
    int eb_t = soff[rcw] + (t - stoff[rcw]) * 64;
    int cnt_t = min(64, soff[rcw + 1] - eb_t);
    if (rcw != r_loaded) { LOADW(rcw) r_loaded = rcw; }

    const char* xb = (const char*)xs[cur];
    f32x4 acc[2][4] = {};   // D: col=edge (lane&15), row=out-channel (g*4+j)
    #pragma unroll
    for (int kk = 0; kk < 4; ++kk) {
      bf16x8 a[4];
      #pragma unroll
      for (int q = 0; q < 4; ++q) {
        int row = q * 16 + ln;
        int kb = kk * 64 + g * 16;
        a[q] = *(const bf16x8*)(xb + row * 256 + (kb ^ ((row & 7) << 4)));
      }
      #pragma unroll
      for (int n = 0; n < 2; ++n)
        #pragma unroll
        for (int q = 0; q < 4; ++q)
          acc[n][q] = __builtin_amdgcn_mfma_f32_16x16x32_bf16(bfr[n][kk], a[q],
                                                              acc[n][q], 0, 0, 0);
    }

    // E: wide cached stores (8B x2 per edge-quarter per lane)
    #pragma unroll
    for (int q = 0; q < 4; ++q) {
      int rr = q * 16 + ln;
      if (rr < cnt_t) {
        ushort* mp = msg + (size_t)wq[q] * OUT_F + wc + g * 4;
        uint2 p0, p1;
        p0.x = (uint)f2bf(acc[0][q][0]) | ((uint)f2bf(acc[0][q][1]) << 16);
        p0.y = (uint)f2bf(acc[0][q][2]) | ((uint)f2bf(acc[0][q][3]) << 16);
        p1.x = (uint)f2bf(acc[1][q][0]) | ((uint)f2bf(acc[1][q][1]) << 16);
        p1.y = (uint)f2bf(acc[1][q][2]) | ((uint)f2bf(acc[1][q][3]) << 16);
        *(uint2*)mp = p0;          // cols wc+g*4 .. +3
        *(uint2*)(mp + 16) = p1;   // cols wc+16+g*4 .. +3
      }
    }

    // A: ds_write x(t+1) regs -> other buffer (visible after next C)
    if (t + 1 < tend) {
      char* xw = (char*)xs[cur ^ 1];
      #pragma unroll
      for (int i = 0; i < 4; ++i) {
        int row = trow + 16 * i;
        *(bf16x8*)(xw + row * 256 + ((ts4 * 16) ^ ((row & 7) << 4))) = xreg[i];
      }
    }

    // B: issue next loads (latency hidden across the next barrier+MFMA)
    if (t + 2 < tend) {
      #pragma unroll
      for (int i = 0; i < 4; ++i)
        xreg[i] = *(const bf16x8*)(xbf + (size_t)srcrow[i] * IN_F + ts4 * 8);
    }
    if (t + 3 < tend) {
      while (t + 3 >= stoff[rw3 + 1]) ++rw3;
      int eb = soff[rw3] + (t + 3 - stoff[rw3]) * 64;
      int cnt = min(64, soff[rw3 + 1] - eb);
      #pragma unroll
      for (int i = 0; i < 4; ++i)
        srcrow[i] = perm[eb + min(trow + 16 * i, cnt - 1)];
    }
    if (t + 1 < tend) {
      while (t + 1 >= stoff[rw1 + 1]) ++rw1;
      int eb = soff[rw1] + (t + 1 - stoff[rw1]) * 64;
      int cnt = min(64, soff[rw1 + 1] - eb);
      #pragma unroll
      for (int q = 0; q < 4; ++q) wq[q] = wpos[eb + min(q * 16 + ln, cnt - 1)];
    }
    cur ^= 1;
  }
#undef LOADW
}

// ---- Kernel 5: fused self MFMA + per-node aggregation + bias + out -----------
__global__ __launch_bounds__(256) void k_out(
    const ushort* __restrict__ xbf, const ushort* __restrict__ swT,
    const float* __restrict__ bias, const ushort* __restrict__ msg,
    const int* __restrict__ row_off, float* __restrict__ out, int N) {
  __shared__ float smem[64 * 128];   // 32 KB; first 16 KB doubles as bf16 x-tile
  __shared__ int rof[65];            // block's row_off slice (kills serial loads)
  int tid = threadIdx.x;
  int base = blockIdx.x * 64;
  int wv = tid >> 6, l = tid & 63;
  char* xb = (char*)smem;

  #pragma unroll
  for (int i = 0; i < 4; ++i) {
    int idx = i * 256 + tid;
    int row = idx >> 4, s4 = idx & 15;
    int c = s4 ^ (row & 7);
    int n = base + row;
    char* lb = xb + i * 4096 + wv * 1024;
    if (n < N)
      gl_lds16(xbf + (size_t)n * IN_F + c * 8, lb);
  }
  if (tid < 65) rof[tid] = row_off[min(base + tid, N)];

  int g = l >> 4, ln = l & 15, wc = wv * 32;
  bf16x8 bfr[2][4];
  #pragma unroll
  for (int n = 0; n < 2; ++n)
    #pragma unroll
    for (int kk = 0; kk < 4; ++kk)
      bfr[n][kk] = *(const bf16x8*)(swT + (wc + n * 16 + ln) * IN_F + kk * 32 + g * 8);

  __syncthreads();

  f32x4 acc[4][2] = {};
  #pragma unroll
  for (int kk = 0; kk < 4; ++kk) {
    bf16x8 a[4];
    #pragma unroll
    for (int m = 0; m < 4; ++m) {
      int row = m * 16 + ln;
      int kb = kk * 64 + g * 16;
      a[m] = *(const bf16x8*)(xb + row * 256 + (kb ^ ((row & 7) << 4)));
    }
    #pragma unroll
    for (int m = 0; m < 4; ++m)
      #pragma unroll
      for (int n = 0; n < 2; ++n)
        acc[m][n] = __builtin_amdgcn_mfma_f32_16x16x32_bf16(a[m], bfr[n][kk],
                                                            acc[m][n], 0, 0, 0);
  }

  __syncthreads();   // all xs reads done; reuse smem as fp32 self-result
  #pragma unroll
  for (int m = 0; m < 4; ++m)
    #pragma unroll
    for (int n = 0; n < 2; ++n)
      #pragma unroll
      for (int j = 0; j < 4; ++j)
        smem[(m * 16 + g * 4 + j) * 128 + wc + n * 16 + ln] = acc[m][n][j];
  __syncthreads();

  // aggregation: lane halves split even/odd rows; 8B/lane; shfl_xor combine
  int half = l >> 5, cl = l & 31;
  f32x4e b4 = ((const f32x4e*)bias)[cl];
  for (int q = 0; q < 16; ++q) {
    int n = base + wv * 16 + q;
    if (n >= N) break;
    int lo = rof[wv * 16 + q], hi = rof[wv * 16 + q + 1];
    int len = hi - lo;
    const ushort* mrow = msg + (size_t)(lo + half) * OUT_F + cl * 4;
    float fa0 = 0.f, fa1 = 0.f, fa2 = 0.f, fa3 = 0.f;
#define ACC8(v)                                                  \
    { fa0 += __uint_as_float((v).x << 16);                       \
      fa1 += __uint_as_float((v).x & 0xFFFF0000u);               \
      fa2 += __uint_as_float((v).y << 16);                       \
      fa3 += __uint_as_float((v).y & 0xFFFF0000u); }
    int p = 0;
    for (; p + 8 <= len; p += 8) {
      u32x2e v0 = *(const u32x2e*)(mrow + (size_t)p * OUT_F);
      u32x2e v1 = *(const u32x2e*)(mrow + (size_t)(p + 2) * OUT_F);
      u32x2e v2 = *(const u32x2e*)(mrow + (size_t)(p + 4) * OUT_F);
      u32x2e v3 = *(const u32x2e*)(mrow + (size_t)(p + 6) * OUT_F);
      ACC8(v0) ACC8(v1) ACC8(v2) ACC8(v3)
    }
    for (; p + 2 <= len; p += 2) {
      u32x2e v = *(const u32x2e*)(mrow + (size_t)p * OUT_F);
      ACC8(v)
    }
    if (p < len && half == 0) {
      u32x2e v = *(const u32x2e*)(mrow + (size_t)p * OUT_F);
      ACC8(v)
    }
#undef ACC8
    fa0 += __shfl_xor(fa0, 32);
    fa1 += __shfl_xor(fa1, 32);
    fa2 += __shfl_xor(fa2, 32);
    fa3 += __shfl_xor(fa3, 32);
    if (half == 0) {
      float inv = 1.f / (float)max(len, 1);
      int rloc = wv * 16 + q;
      f32x4e s4 = *(const f32x4e*)(&smem[rloc * 128 + cl * 4]);
      f32x4e o = {fa0 * inv + s4.x + b4.x, fa1 * inv + s4.y + b4.y,
                  fa2 * inv + s4.z + b4.z, fa3 * inv + s4.w + b4.w};
      __builtin_nontemporal_store(o, (f32x4e*)(out + (size_t)n * OUT_F + cl * 4));
    }
  }
}

// ------------------------------- launch ---------------------------------------
extern "C" void kernel_launch(void* const* d_in, const int* in_sizes, int n_in,
                              void* d_out, int out_size, void* d_ws, size_t ws_size,
                              hipStream_t stream) {
  const float* x      = (const float*)d_in[0];
  const int*   ei     = (const int*)d_in[1];   // [2][E]
  const int*   etype  = (const int*)d_in[2];   // [E]
  const float* weight = (const float*)d_in[4]; // [B][128][128]
  const float* coeff  = (const float*)d_in[5]; // [R][B]
  const float* selfw  = (const float*)d_in[6]; // [128][128]
  const float* bias   = (const float*)d_in[7]; // [128]

  int N = in_sizes[0] / IN_F;
  int E = in_sizes[2];
  int B = in_sizes[4] / (IN_F * OUT_F);
  int R = in_sizes[5] / B;
  const int* src = ei;
  const int* tgt = ei + E;

  char* ws = (char*)d_ws;
  size_t off = 0;
  auto alloc = [&](size_t bytes) {
    char* p = ws + off;
    off += (bytes + 255) & ~(size_t)255;
    return p;
  };
  ushort* rwT     = (ushort*)alloc((size_t)(R + 1) * IN_F * OUT_F * 2);
  ushort* xbf     = (ushort*)alloc((size_t)N * IN_F * 2);
  int*    perm    = (int*)alloc((size_t)E * 4);
  int*    wpos    = (int*)alloc((size_t)E * 4);
  int*    row_off = (int*)alloc((size_t)(N + 1) * 4);
  // zero region: ideg[N] | cursor_tgt[N] | hist[64] | cursor_rel[64]
  int*    ideg    = (int*)alloc((size_t)(2 * N + 128) * 4);
  int*    cur_t   = ideg + N;
  int*    hist    = cur_t + N;
  int*    cur_r   = hist + 64;
  int*    offs    = (int*)alloc(64 * 4);
  int*    toffs   = (int*)alloc(64 * 4);
  ushort* msg     = (ushort*)alloc((size_t)E * OUT_F * 2);

  (void)hipMemsetAsync(ideg, 0, (size_t)(2 * N + 128) * 4, stream);

  int n4 = N * IN_F / 4;
  int wblocks = (R + 1) * 4;
  int xblocks = (n4 + 255) / 256;
  int hblocks = (E + 255) / 256;
  k_prep<<<wblocks + xblocks + hblocks, 256, 0, stream>>>(
      weight, coeff, selfw, rwT, x, xbf, n4, etype, tgt, E, R, B,
      hist, ideg, wblocks, xblocks);
  k_scans<<<1, 1024, 0, stream>>>(hist, offs, toffs, R, ideg, row_off, N);
  int scblocks = (E + SC_CHUNK - 1) / SC_CHUNK;
  k_scatter2<<<scblocks, 256, 0, stream>>>(etype, src, tgt, E, R, offs, row_off,
                                           cur_r, cur_t, perm, wpos);
  k_msg<<<MSG_GRID, 256, 0, stream>>>(xbf, perm, wpos, offs, toffs, rwT, msg, R);
  k_out<<<(N + 63) / 64, 256, 0, stream>>>(xbf, rwT + (size_t)R * IN_F * OUT_F,
                                           bias, msg, row_off, (float*)d_out, N);
}

// Round 14
// 271.755 us; speedup vs baseline: 1.2925x; 1.0117x over previous
//
#include <hip/hip_runtime.h>

#define IN_F 128
#define OUT_F 128
#define MSG_GRID 2048
#define SC_CHUNK 1536

typedef unsigned int uint;
typedef unsigned short ushort;
typedef __attribute__((ext_vector_type(8))) short bf16x8;
typedef __attribute__((ext_vector_type(4))) float f32x4;
typedef __attribute__((ext_vector_type(4))) float f32x4e;
typedef __attribute__((ext_vector_type(2))) float f32x2e;
typedef __attribute__((ext_vector_type(4))) int i32x4;
typedef __attribute__((ext_vector_type(2))) uint u32x2e;

typedef __attribute__((address_space(1))) void gvoid;
typedef __attribute__((address_space(3))) void svoid;

__device__ __forceinline__ void gl_lds16(const void* g, void* l) {
  __builtin_amdgcn_global_load_lds((const gvoid*)g, (svoid*)l, 16, 0, 0);
}

__device__ inline ushort f2bf(float f) {
  uint u = __float_as_uint(f);
  uint r = (u + 0x7FFFu + ((u >> 16) & 1u)) >> 16;
  return (ushort)r;
}

// ---- Kernel 1: fused {basis-combine+transpose+bf16 weights | x->bf16 | hist/deg}
__global__ __launch_bounds__(256) void k_prep(
    const float* __restrict__ w, const float* __restrict__ coef,
    const float* __restrict__ selfw, ushort* __restrict__ rwT,
    const float* __restrict__ x, ushort* __restrict__ xbf, int n4,
    const int* __restrict__ etype, const int* __restrict__ tgt, int E, int R, int B,
    int* __restrict__ hist, int* __restrict__ ideg, int wblocks, int xblocks) {
  __shared__ float t[64][65];
  __shared__ int lh[64];
  int tid = threadIdx.x;
  int bid = blockIdx.x;

  if (bid < wblocks) {                       // weight-prep role
    int r = bid >> 2;
    int i0 = (bid & 1) * 64;
    int o0 = ((bid >> 1) & 1) * 64;
    float4 a4[4];
    if (r < R) {
      #pragma unroll
      for (int it = 0; it < 4; ++it) a4[it] = make_float4(0.f, 0.f, 0.f, 0.f);
      for (int b = 0; b < B; ++b) {
        float cb = coef[r * B + b];
        const float4* w4 = (const float4*)w + (size_t)b * 4096;
        #pragma unroll
        for (int it = 0; it < 4; ++it) {
          int idx = it * 256 + tid;
          int i = idx >> 4, c4 = idx & 15;
          float4 v = w4[(i0 + i) * 32 + (o0 >> 2) + c4];
          a4[it].x = fmaf(cb, v.x, a4[it].x);
          a4[it].y = fmaf(cb, v.y, a4[it].y);
          a4[it].z = fmaf(cb, v.z, a4[it].z);
          a4[it].w = fmaf(cb, v.w, a4[it].w);
        }
      }
    } else {
      const float4* w4 = (const float4*)selfw;
      #pragma unroll
      for (int it = 0; it < 4; ++it) {
        int idx = it * 256 + tid;
        int i = idx >> 4, c4 = idx & 15;
        a4[it] = w4[(i0 + i) * 32 + (o0 >> 2) + c4];
      }
    }
    #pragma unroll
    for (int it = 0; it < 4; ++it) {
      int idx = it * 256 + tid;
      int i = idx >> 4, c4 = idx & 15;
      t[i][c4 * 4 + 0] = a4[it].x; t[i][c4 * 4 + 1] = a4[it].y;
      t[i][c4 * 4 + 2] = a4[it].z; t[i][c4 * 4 + 3] = a4[it].w;
    }
    __syncthreads();
    ushort* dst = rwT + (size_t)r * IN_F * OUT_F;
    #pragma unroll
    for (int it = 0; it < 4; ++it) {
      int idx = it * 256 + tid;
      int o = idx >> 4, cc = idx & 15;
      uint2 pk;
      pk.x = (uint)f2bf(t[cc * 4 + 0][o]) | ((uint)f2bf(t[cc * 4 + 1][o]) << 16);
      pk.y = (uint)f2bf(t[cc * 4 + 2][o]) | ((uint)f2bf(t[cc * 4 + 3][o]) << 16);
      *(uint2*)(dst + (o0 + o) * IN_F + i0 + cc * 4) = pk;
    }
    return;
  }
  bid -= wblocks;
  if (bid < xblocks) {                        // x conversion role
    int i = bid * 256 + tid;
    if (i < n4) {
      f32x4e v = __builtin_nontemporal_load((const f32x4e*)x + i);
      uint2 pk;
      pk.x = (uint)f2bf(v.x) | ((uint)f2bf(v.y) << 16);
      pk.y = (uint)f2bf(v.z) | ((uint)f2bf(v.w) << 16);
      ((uint2*)xbf)[i] = pk;
    }
    return;
  }
  bid -= xblocks;                             // histogram + degree role
  if (tid < R) lh[tid] = 0;
  __syncthreads();
  int e = bid * 256 + tid;
  if (e < E) {
    atomicAdd(&lh[etype[e]], 1);
    atomicAdd(&ideg[tgt[e]], 1);
  }
  __syncthreads();
  if (tid < R && lh[tid]) atomicAdd(&hist[tid], lh[tid]);
}

// ---- Kernel 2: R-bin scan + node-degree exclusive scan -----------------------
__global__ __launch_bounds__(1024) void k_scans(
    const int* __restrict__ hist, int* __restrict__ offs, int* __restrict__ toffs,
    int R, const int* __restrict__ ideg, int* __restrict__ row_off, int N) {
  __shared__ int part[1024];
  int tid = threadIdx.x;
  if (tid == 0) {
    int s = 0, tt = 0;
    for (int r = 0; r < R; ++r) {
      offs[r] = s; toffs[r] = tt;
      s += hist[r];
      tt += (hist[r] + 63) >> 6;
    }
    offs[R] = s; toffs[R] = tt;
  }
  int chunk = (((N + 1023) >> 10) + 3) & ~3;
  int lo = min(tid * chunk, N), hi = min(lo + chunk, N);
  int s = 0;
  int i = lo;
  for (; i + 4 <= hi; i += 4) {
    i32x4 v = *(const i32x4*)(ideg + i);
    s += v.x + v.y + v.z + v.w;
  }
  for (; i < hi; ++i) s += ideg[i];
  part[tid] = s;
  __syncthreads();
  for (int d = 1; d < 1024; d <<= 1) {
    int v = (tid >= d) ? part[tid - d] : 0;
    __syncthreads();
    part[tid] += v;
    __syncthreads();
  }
  int pre = (tid > 0) ? part[tid - 1] : 0;
  i = lo;
  for (; i + 4 <= hi; i += 4) {
    i32x4 v = *(const i32x4*)(ideg + i);
    i32x4 o;
    o.x = pre; o.y = pre + v.x; o.z = o.y + v.y; o.w = o.z + v.z;
    pre = o.w + v.w;
    *(i32x4*)(row_off + i) = o;
  }
  for (; i < hi; ++i) { row_off[i] = pre; pre += ideg[i]; }
  if (tid == 1023) row_off[N] = part[1023];
}

// ---- Kernel 3: counting-sort scatter, chunked (low cur_r contention) ---------
__global__ __launch_bounds__(256) void k_scatter2(
    const int* __restrict__ etype, const int* __restrict__ src,
    const int* __restrict__ tgt, int E, int R,
    const int* __restrict__ offs, const int* __restrict__ row_off,
    int* __restrict__ cur_r, int* __restrict__ cur_t,
    int* __restrict__ perm, int* __restrict__ wpos) {
  __shared__ int lh[64], lbase[64], lcur[64];
  __shared__ unsigned char ety[SC_CHUNK];
  int tid = threadIdx.x;
  int e0 = blockIdx.x * SC_CHUNK;
  int e1 = min(e0 + SC_CHUNK, E);
  if (e0 >= E) return;
  if (tid < R) { lh[tid] = 0; lcur[tid] = 0; }
  __syncthreads();
  for (int e = e0 + tid; e < e1; e += 256) {
    int t = etype[e];
    ety[e - e0] = (unsigned char)t;
    atomicAdd(&lh[t], 1);
  }
  __syncthreads();
  if (tid < R && lh[tid]) lbase[tid] = atomicAdd(&cur_r[tid], lh[tid]);
  __syncthreads();
  for (int e = e0 + tid; e < e1; e += 256) {
    int t = ety[e - e0];
    int loc = atomicAdd(&lcur[t], 1);
    int slot = offs[t] + lbase[t] + loc;
    perm[slot] = src[e];
    int tg = tgt[e];
    wpos[slot] = row_off[tg] + atomicAdd(&cur_t[tg], 1);
  }
}

// ---- Kernel 4: persistent reg-staged double-buffered MFMA msg GEMM -----------
// (round-8 proven version) Sync: ONE {lgkmcnt(0); s_barrier; sched_barrier(0)}
// per tile. All global traffic is private VGPR loads/stores — compiler-tracked.
__global__ __launch_bounds__(256) void k_msg(
    const ushort* __restrict__ xbf, const int* __restrict__ perm,
    const int* __restrict__ wpos, const int* __restrict__ offs,
    const int* __restrict__ toffs, const ushort* __restrict__ rwT,
    ushort* __restrict__ msg, int R) {
  __shared__ ushort xs[2][64 * IN_F];   // 32 KB double buffer (XOR-swizzled)
  __shared__ int soff[48], stoff[48];
  int tid = threadIdx.x, wv = tid >> 6, l = tid & 63, g = l >> 4, ln = l & 15;
  int wc = wv * 32;
  int trow = tid >> 4, ts4 = tid & 15;

  if (tid <= R) { soff[tid] = offs[tid]; stoff[tid] = toffs[tid]; }
  __syncthreads();
  int ntiles = stoff[R];
  int chunkT = (ntiles + MSG_GRID - 1) / MSG_GRID;
  int t0 = blockIdx.x * chunkT;
  int tend = min(t0 + chunkT, ntiles);
  if (t0 >= tend) return;

  bf16x8 bfr[2][4];
#define LOADW(rr)                                                             \
  {                                                                           \
    const ushort* _wp = rwT + (size_t)(rr) * IN_F * OUT_F;                    \
    _Pragma("unroll")                                                         \
    for (int _n = 0; _n < 2; ++_n)                                            \
      _Pragma("unroll")                                                       \
      for (int _kk = 0; _kk < 4; ++_kk)                                       \
        bfr[_n][_kk] = *(const bf16x8*)(_wp + (wc + _n * 16 + ln) * IN_F +    \
                                        _kk * 32 + g * 8);                    \
  }

  // ---- prologue: fill pipeline (depth 3: perm -> x regs -> ds_write) ----
  int r0 = 0;
  while (t0 >= stoff[r0 + 1]) ++r0;

  bf16x8 xreg[4];
  int srcrow[4], wq[4];

  {
    int eb = soff[r0] + (t0 - stoff[r0]) * 64;
    int cnt = min(64, soff[r0 + 1] - eb);
    #pragma unroll
    for (int i = 0; i < 4; ++i) {
      int row = trow + 16 * i;
      int sr = perm[eb + min(row, cnt - 1)];
      xreg[i] = *(const bf16x8*)(xbf + (size_t)sr * IN_F + ts4 * 8);
    }
    #pragma unroll
    for (int i = 0; i < 4; ++i) {
      int row = trow + 16 * i;
      *(bf16x8*)((char*)xs[0] + row * 256 + ((ts4 * 16) ^ ((row & 7) << 4))) = xreg[i];
    }
    #pragma unroll
    for (int q = 0; q < 4; ++q) wq[q] = wpos[eb + min(q * 16 + ln, cnt - 1)];
  }
  if (t0 + 1 < tend) {
    int r1 = r0; while (t0 + 1 >= stoff[r1 + 1]) ++r1;
    int eb = soff[r1] + (t0 + 1 - stoff[r1]) * 64;
    int cnt = min(64, soff[r1 + 1] - eb);
    #pragma unroll
    for (int i = 0; i < 4; ++i) {
      int row = trow + 16 * i;
      int sr = perm[eb + min(row, cnt - 1)];
      xreg[i] = *(const bf16x8*)(xbf + (size_t)sr * IN_F + ts4 * 8);
    }
  }
  if (t0 + 2 < tend) {
    int r2 = r0; while (t0 + 2 >= stoff[r2 + 1]) ++r2;
    int eb = soff[r2] + (t0 + 2 - stoff[r2]) * 64;
    int cnt = min(64, soff[r2 + 1] - eb);
    #pragma unroll
    for (int i = 0; i < 4; ++i)
      srcrow[i] = perm[eb + min(trow + 16 * i, cnt - 1)];
  }
  LOADW(r0)
  int r_loaded = r0;
  int rcw = r0, rw1 = r0, rw3 = r0;   // walkers for t, t+1, t+3 (monotone)
  int cur = 0;

  for (int t = t0; t < tend; ++t) {
    // C: the one barrier per tile — drains LDS writes AND reads (RAW + WAR)
    asm volatile("s_waitcnt lgkmcnt(0)" ::: "memory");
    __builtin_amdgcn_s_barrier();
    __builtin_amdgcn_sched_barrier(0);

    // D: tile meta + W fragments (rare relation change), then MFMA
    while (t >= stoff[rcw + 1]) ++rcw;
    int eb_t = soff[rcw] + (t - stoff[rcw]) * 64;
    int cnt_t = min(64, soff[rcw + 1] - eb_t);
    if (rcw != r_loaded) { LOADW(rcw) r_loaded = rcw; }

    const char* xb = (const char*)xs[cur];
    f32x4 acc[2][4] = {};   // D: col=edge (lane&15), row=out-channel (g*4+j)
    #pragma unroll
    for (int kk = 0; kk < 4; ++kk) {
      bf16x8 a[4];
      #pragma unroll
      for (int q = 0; q < 4; ++q) {
        int row = q * 16 + ln;
        int kb = kk * 64 + g * 16;
        a[q] = *(const bf16x8*)(xb + row * 256 + (kb ^ ((row & 7) << 4)));
      }
      #pragma unroll
      for (int n = 0; n < 2; ++n)
        #pragma unroll
        for (int q = 0; q < 4; ++q)
          acc[n][q] = __builtin_amdgcn_mfma_f32_16x16x32_bf16(bfr[n][kk], a[q],
                                                              acc[n][q], 0, 0, 0);
    }

    // E: wide cached stores (8B x2 per edge-quarter per lane)
    #pragma unroll
    for (int q = 0; q < 4; ++q) {
      int rr = q * 16 + ln;
      if (rr < cnt_t) {
        ushort* mp = msg + (size_t)wq[q] * OUT_F + wc + g * 4;
        uint2 p0, p1;
        p0.x = (uint)f2bf(acc[0][q][0]) | ((uint)f2bf(acc[0][q][1]) << 16);
        p0.y = (uint)f2bf(acc[0][q][2]) | ((uint)f2bf(acc[0][q][3]) << 16);
        p1.x = (uint)f2bf(acc[1][q][0]) | ((uint)f2bf(acc[1][q][1]) << 16);
        p1.y = (uint)f2bf(acc[1][q][2]) | ((uint)f2bf(acc[1][q][3]) << 16);
        *(uint2*)mp = p0;          // cols wc+g*4 .. +3
        *(uint2*)(mp + 16) = p1;   // cols wc+16+g*4 .. +3
      }
    }

    // A: ds_write x(t+1) regs -> other buffer (visible after next C)
    if (t + 1 < tend) {
      char* xw = (char*)xs[cur ^ 1];
      #pragma unroll
      for (int i = 0; i < 4; ++i) {
        int row = trow + 16 * i;
        *(bf16x8*)(xw + row * 256 + ((ts4 * 16) ^ ((row & 7) << 4))) = xreg[i];
      }
    }

    // B: issue next loads (latency hidden across the next barrier+MFMA)
    if (t + 2 < tend) {
      #pragma unroll
      for (int i = 0; i < 4; ++i)
        xreg[i] = *(const bf16x8*)(xbf + (size_t)srcrow[i] * IN_F + ts4 * 8);
    }
    if (t + 3 < tend) {
      while (t + 3 >= stoff[rw3 + 1]) ++rw3;
      int eb = soff[rw3] + (t + 3 - stoff[rw3]) * 64;
      int cnt = min(64, soff[rw3 + 1] - eb);
      #pragma unroll
      for (int i = 0; i < 4; ++i)
        srcrow[i] = perm[eb + min(trow + 16 * i, cnt - 1)];
    }
    if (t + 1 < tend) {
      while (t + 1 >= stoff[rw1 + 1]) ++rw1;
      int eb = soff[rw1] + (t + 1 - stoff[rw1]) * 64;
      int cnt = min(64, soff[rw1 + 1] - eb);
      #pragma unroll
      for (int q = 0; q < 4; ++q) wq[q] = wpos[eb + min(q * 16 + ln, cnt - 1)];
    }
    cur ^= 1;
  }
#undef LOADW
}

// ---- Kernel 5: fused self MFMA + per-node aggregation + bias + out -----------
__global__ __launch_bounds__(256) void k_out(
    const ushort* __restrict__ xbf, const ushort* __restrict__ swT,
    const float* __restrict__ bias, const ushort* __restrict__ msg,
    const int* __restrict__ row_off, float* __restrict__ out, int N) {
  __shared__ float smem[64 * 128];   // 32 KB; first 16 KB doubles as bf16 x-tile
  __shared__ int rof[65];            // block's row_off slice (kills serial loads)
  int tid = threadIdx.x;
  int base = blockIdx.x * 64;
  int wv = tid >> 6, l = tid & 63;
  char* xb = (char*)smem;

  #pragma unroll
  for (int i = 0; i < 4; ++i) {
    int idx = i * 256 + tid;
    int row = idx >> 4, s4 = idx & 15;
    int c = s4 ^ (row & 7);
    int n = base + row;
    char* lb = xb + i * 4096 + wv * 1024;
    if (n < N)
      gl_lds16(xbf + (size_t)n * IN_F + c * 8, lb);
  }
  if (tid < 65) rof[tid] = row_off[min(base + tid, N)];

  int g = l >> 4, ln = l & 15, wc = wv * 32;
  bf16x8 bfr[2][4];
  #pragma unroll
  for (int n = 0; n < 2; ++n)
    #pragma unroll
    for (int kk = 0; kk < 4; ++kk)
      bfr[n][kk] = *(const bf16x8*)(swT + (wc + n * 16 + ln) * IN_F + kk * 32 + g * 8);

  __syncthreads();

  f32x4 acc[4][2] = {};
  #pragma unroll
  for (int kk = 0; kk < 4; ++kk) {
    bf16x8 a[4];
    #pragma unroll
    for (int m = 0; m < 4; ++m) {
      int row = m * 16 + ln;
      int kb = kk * 64 + g * 16;
      a[m] = *(const bf16x8*)(xb + row * 256 + (kb ^ ((row & 7) << 4)));
    }
    #pragma unroll
    for (int m = 0; m < 4; ++m)
      #pragma unroll
      for (int n = 0; n < 2; ++n)
        acc[m][n] = __builtin_amdgcn_mfma_f32_16x16x32_bf16(a[m], bfr[n][kk],
                                                            acc[m][n], 0, 0, 0);
  }

  __syncthreads();   // all xs reads done; reuse smem as fp32 self-result
  #pragma unroll
  for (int m = 0; m < 4; ++m)
    #pragma unroll
    for (int n = 0; n < 2; ++n)
      #pragma unroll
      for (int j = 0; j < 4; ++j)
        smem[(m * 16 + g * 4 + j) * 128 + wc + n * 16 + ln] = acc[m][n][j];
  __syncthreads();

  // aggregation: lane halves split even/odd rows; 8B/lane; shfl_xor combine
  int half = l >> 5, cl = l & 31;
  f32x4e b4 = ((const f32x4e*)bias)[cl];
  for (int q = 0; q < 16; ++q) {
    int n = base + wv * 16 + q;
    if (n >= N) break;
    int lo = rof[wv * 16 + q], hi = rof[wv * 16 + q + 1];
    int len = hi - lo;
    const ushort* mrow = msg + (size_t)(lo + half) * OUT_F + cl * 4;
    float fa0 = 0.f, fa1 = 0.f, fa2 = 0.f, fa3 = 0.f;
#define ACC8(v)                                                  \
    { fa0 += __uint_as_float((v).x << 16);                       \
      fa1 += __uint_as_float((v).x & 0xFFFF0000u);               \
      fa2 += __uint_as_float((v).y << 16);                       \
      fa3 += __uint_as_float((v).y & 0xFFFF0000u); }
    int p = 0;
    for (; p + 8 <= len; p += 8) {
      u32x2e v0 = *(const u32x2e*)(mrow + (size_t)p * OUT_F);
      u32x2e v1 = *(const u32x2e*)(mrow + (size_t)(p + 2) * OUT_F);
      u32x2e v2 = *(const u32x2e*)(mrow + (size_t)(p + 4) * OUT_F);
      u32x2e v3 = *(const u32x2e*)(mrow + (size_t)(p + 6) * OUT_F);
      ACC8(v0) ACC8(v1) ACC8(v2) ACC8(v3)
    }
    for (; p + 2 <= len; p += 2) {
      u32x2e v = *(const u32x2e*)(mrow + (size_t)p * OUT_F);
      ACC8(v)
    }
    if (p < len && half == 0) {
      u32x2e v = *(const u32x2e*)(mrow + (size_t)p * OUT_F);
      ACC8(v)
    }
#undef ACC8
    fa0 += __shfl_xor(fa0, 32);
    fa1 += __shfl_xor(fa1, 32);
    fa2 += __shfl_xor(fa2, 32);
    fa3 += __shfl_xor(fa3, 32);
    if (half == 0) {
      float inv = 1.f / (float)max(len, 1);
      int rloc = wv * 16 + q;
      f32x4e s4 = *(const f32x4e*)(&smem[rloc * 128 + cl * 4]);
      f32x4e o = {fa0 * inv + s4.x + b4.x, fa1 * inv + s4.y + b4.y,
                  fa2 * inv + s4.z + b4.z, fa3 * inv + s4.w + b4.w};
      __builtin_nontemporal_store(o, (f32x4e*)(out + (size_t)n * OUT_F + cl * 4));
    }
  }
}

// ------------------------------- launch ---------------------------------------
extern "C" void kernel_launch(void* const* d_in, const int* in_sizes, int n_in,
                              void* d_out, int out_size, void* d_ws, size_t ws_size,
                              hipStream_t stream) {
  const float* x      = (const float*)d_in[0];
  const int*   ei     = (const int*)d_in[1];   // [2][E]
  const int*   etype  = (const int*)d_in[2];   // [E]
  const float* weight = (const float*)d_in[4]; // [B][128][128]
  const float* coeff  = (const float*)d_in[5]; // [R][B]
  const float* selfw  = (const float*)d_in[6]; // [128][128]
  const float* bias   = (const float*)d_in[7]; // [128]

  int N = in_sizes[0] / IN_F;
  int E = in_sizes[2];
  int B = in_sizes[4] / (IN_F * OUT_F);
  int R = in_sizes[5] / B;
  const int* src = ei;
  const int* tgt = ei + E;

  char* ws = (char*)d_ws;
  size_t off = 0;
  auto alloc = [&](size_t bytes) {
    char* p = ws + off;
    off += (bytes + 255) & ~(size_t)255;
    return p;
  };
  ushort* rwT     = (ushort*)alloc((size_t)(R + 1) * IN_F * OUT_F * 2);
  ushort* xbf     = (ushort*)alloc((size_t)N * IN_F * 2);
  int*    perm    = (int*)alloc((size_t)E * 4);
  int*    wpos    = (int*)alloc((size_t)E * 4);
  int*    row_off = (int*)alloc((size_t)(N + 1) * 4);
  // zero region: ideg[N] | cursor_tgt[N] | hist[64] | cursor_rel[64]
  int*    ideg    = (int*)alloc((size_t)(2 * N + 128) * 4);
  int*    cur_t   = ideg + N;
  int*    hist    = cur_t + N;
  int*    cur_r   = hist + 64;
  int*    offs    = (int*)alloc(64 * 4);
  int*    toffs   = (int*)alloc(64 * 4);
  ushort* msg     = (ushort*)alloc((size_t)E * OUT_F * 2);

  (void)hipMemsetAsync(ideg, 0, (size_t)(2 * N + 128) * 4, stream);

  int n4 = N * IN_F / 4;
  int wblocks = (R + 1) * 4;
  int xblocks = (n4 + 255) / 256;
  int hblocks = (E + 255) / 256;
  k_prep<<<wblocks + xblocks + hblocks, 256, 0, stream>>>(
      weight, coeff, selfw, rwT, x, xbf, n4, etype, tgt, E, R, B,
      hist, ideg, wblocks, xblocks);
  k_scans<<<1, 1024, 0, stream>>>(hist, offs, toffs, R, ideg, row_off, N);
  int scblocks = (E + SC_CHUNK - 1) / SC_CHUNK;
  k_scatter2<<<scblocks, 256, 0, stream>>>(etype, src, tgt, E, R, offs, row_off,
                                           cur_r, cur_t, perm, wpos);
  k_msg<<<MSG_GRID, 256, 0, stream>>>(xbf, perm, wpos, offs, toffs, rwT, msg, R);
  k_out<<<(N + 63) / 64, 256, 0, stream>>>(xbf, rwT + (size_t)R * IN_F * OUT_F,
                                           bias, msg, row_off, (float*)d_out, N);
}